// Round 13
// baseline (69.182 us; speedup 1.0000x reference)
//
#include <hip/hip_runtime.h>
#include <hip/hip_bf16.h>

typedef __bf16 bf16_t;
typedef __bf16 bf16x4 __attribute__((ext_vector_type(4)));
typedef __bf16 bf16x8 __attribute__((ext_vector_type(8)));
typedef float  f32x4  __attribute__((ext_vector_type(4)));
typedef short  short4v __attribute__((ext_vector_type(4)));

#define GLL(gp, lp) __builtin_amdgcn_global_load_lds((const __attribute__((address_space(1))) void*)(gp), (__attribute__((address_space(3))) void*)(lp), 16, 0, 0)

__device__ __forceinline__ f32x4 mfma16x16x16_bf16(bf16x4 a, bf16x4 b, f32x4 c) {
#if __has_builtin(__builtin_amdgcn_mfma_f32_16x16x16_bf16)
    return __builtin_amdgcn_mfma_f32_16x16x16_bf16(a, b, c, 0, 0, 0);
#else
    return __builtin_amdgcn_mfma_f32_16x16x16bf16_1k(__builtin_bit_cast(short4v, a), __builtin_bit_cast(short4v, b), c, 0, 0, 0);
#endif
}

__device__ __forceinline__ float fexp2(float x) {
#if __has_builtin(__builtin_amdgcn_exp2f)
    return __builtin_amdgcn_exp2f(x);
#else
    return exp2f(x);
#endif
}

// ---------------- kernel 0: f32 -> bf16 convert ----------------
__global__ __launch_bounds__(256) void cvt_kernel(const float* __restrict__ x,
                                                  const float* __restrict__ wq,
                                                  const float* __restrict__ wk,
                                                  const float* __restrict__ wv,
                                                  bf16_t* __restrict__ xb,
                                                  bf16_t* __restrict__ wall) {
    const int TOT4 = 1245184;
    for (int i = blockIdx.x * blockDim.x + threadIdx.x; i < TOT4; i += gridDim.x * blockDim.x) {
        const float* src; bf16_t* dst; int off;
        if (i < 1048576) { src = x; dst = xb; off = i; }
        else {
            int j = i - 1048576;
            int wsel = j >> 16;
            off = j & 65535;
            src = (wsel == 0) ? wq : ((wsel == 1) ? wk : wv);
            dst = wall + ((size_t)wsel << 18);
        }
        float4 v = *(const float4*)(src + (size_t)off * 4);
        bf16x4 o = { (bf16_t)v.x, (bf16_t)v.y, (bf16_t)v.z, (bf16_t)v.w };
        *(bf16x4*)(dst + (size_t)off * 4) = o;
    }
}

// ---------------- kernel 1: fused QKV projection GEMM v3 (swizzled, verified R9/R10) ------
__global__ __launch_bounds__(256) void proj_kernel(const bf16_t* __restrict__ xb,
                                                   const bf16_t* __restrict__ wall,
                                                   bf16_t* __restrict__ Qb,
                                                   bf16_t* __restrict__ Kb,
                                                   bf16_t* __restrict__ Vt) {
    __shared__ char psm[34816];

    const int tid = threadIdx.x;
    const int w = tid >> 6, lane = tid & 63;
    const int bx = blockIdx.x;
    const int nb = bx % 12, mb = bx / 12;
    const int n0 = nb * 128, m0 = mb * 128;
    const int wn = w & 1, wm = w >> 1;
    const int l15 = lane & 15, g = lane >> 4;

    const int srow = w * 32 + (lane >> 2);
    const int kcol = (((lane & 3) ^ ((lane >> 3) & 3)) << 3);   // inverse-swizzled k-unit
    const bf16_t* wsrc0 = wall + (size_t)(n0 + srow) * 512 + kcol;
    const bf16_t* xsrc0 = xb + (size_t)(m0 + srow) * 512 + kcol;

    f32x4 acc[4][4] = {};

    {
        bf16_t* lw = (bf16_t*)(psm) + w * 1024;
        bf16_t* lx = (bf16_t*)(psm + 8192) + w * 1024;
        GLL(wsrc0, lw);
        GLL(wsrc0 + 8192, lw + 512);
        GLL(xsrc0, lx);
        GLL(xsrc0 + 8192, lx + 512);
    }
    __syncthreads();

    const int s4 = (l15 >> 1) & 3;   // read-side unit swizzle key

    for (int kt = 0; kt < 16; ++kt) {
        const int buf = kt & 1;
        if (kt < 15) {
            const int ko = (kt + 1) * 32;
            bf16_t* lw = (bf16_t*)(psm + (buf ^ 1) * 16384) + w * 1024;
            bf16_t* lx = (bf16_t*)(psm + (buf ^ 1) * 16384 + 8192) + w * 1024;
            GLL(wsrc0 + ko, lw);
            GLL(wsrc0 + 8192 + ko, lw + 512);
            GLL(xsrc0 + ko, lx);
            GLL(xsrc0 + 8192 + ko, lx + 512);
        }
        const bf16_t* sW = (const bf16_t*)(psm + buf * 16384);
        const bf16_t* sX = (const bf16_t*)(psm + buf * 16384 + 8192);

        bf16x8 af[4], bfv[4];
#pragma unroll
        for (int ni = 0; ni < 4; ++ni)
            af[ni] = *(const bf16x8*)(sW + (wn * 64 + ni * 16 + l15) * 32 + ((g ^ s4) << 3));
#pragma unroll
        for (int mi = 0; mi < 4; ++mi)
            bfv[mi] = *(const bf16x8*)(sX + (wm * 64 + mi * 16 + l15) * 32 + ((g ^ s4) << 3));
#pragma unroll
        for (int ni = 0; ni < 4; ++ni)
#pragma unroll
            for (int mi = 0; mi < 4; ++mi)
                acc[ni][mi] = __builtin_amdgcn_mfma_f32_16x16x32_bf16(af[ni], bfv[mi], acc[ni][mi], 0, 0, 0);
        __syncthreads();
    }

    const int which = n0 >> 9;   // 0=Q, 1=K, 2=V
    if (which < 2) {
        bf16_t* dst = (which == 0) ? Qb : Kb;
#pragma unroll
        for (int ni = 0; ni < 4; ++ni) {
#pragma unroll
            for (int mi = 0; mi < 4; ++mi) {
                int j = (n0 & 511) + wn * 64 + ni * 16 + g * 4;
                int h = j >> 6, dd = j & 63;
                int sb = m0 + wm * 64 + mi * 16 + l15;
                int b = sb >> 10, s = sb & 1023;
                bf16x4 o = { (bf16_t)acc[ni][mi][0], (bf16_t)acc[ni][mi][1],
                             (bf16_t)acc[ni][mi][2], (bf16_t)acc[ni][mi][3] };
                *(bf16x4*)(dst + ((size_t)((b * 8 + h) * 1024 + s)) * 64 + dd) = o;
            }
        }
    } else {
        bf16_t* ctile = (bf16_t*)psm;
#pragma unroll
        for (int ni = 0; ni < 4; ++ni)
#pragma unroll
            for (int mi = 0; mi < 4; ++mi)
#pragma unroll
                for (int r = 0; r < 4; ++r)
                    ctile[(wn * 64 + ni * 16 + g * 4 + r) * 136 + wm * 64 + mi * 16 + l15] =
                        (bf16_t)acc[ni][mi][r];
        __syncthreads();
        const int rr = tid >> 1, half = tid & 1;
        const int jv = (n0 & 511) + rr;
        const int hh = jv >> 6, dd = jv & 63;
        const int b = m0 >> 10, sb = (m0 & 1023) + half * 64;
        bf16_t* dst = Vt + ((size_t)((b * 8 + hh) * 64 + dd)) * 1024 + sb;
        const bf16_t* src = ctile + rr * 136 + half * 64;
#pragma unroll
        for (int u = 0; u < 8; ++u)
            *(bf16x8*)(dst + u * 8) = *(const bf16x8*)(src + u * 8);
    }
}

// ---------------- kernel 2: flash attention v8 ----------------
// v5 skeleton (resident K/V, 2 phases of 512 keys, 3 barriers, grid 256, 8 waves)
// + VALU denominator (removes the 2 ones-MFMAs per sub = 20% of MFMA issue slots)
// + s_setprio(1) around the PV MFMA cluster (T5).
__global__ __launch_bounds__(512, 2) void attn_kernel(const bf16_t* __restrict__ Qb,
                                                      const bf16_t* __restrict__ Kb,
                                                      const bf16_t* __restrict__ Vt,
                                                      bf16_t* __restrict__ Ob) {
    __shared__ char smK[65536];   // [512 keys][128B], 16B units XOR-swizzled by (row&7)
    __shared__ char smV[65536];   // [64 d][1024B],    16B units XOR-swizzled by (row&7)
    const int tid = threadIdx.x;
    const int w = tid >> 6, lane = tid & 63;
    const int l15 = lane & 15, g = lane >> 4, l7 = lane & 7;

    const int bx = blockIdx.x;        // 256
    const int head = bx & 63;         // bx&7 = head&7 -> XCD-local head group
    const int qq = bx >> 6;           // 0..3
    const int q0 = qq * 256 + w * 32;

    const size_t hoff = (size_t)head << 16;
    const bf16_t* Qh = Qb + hoff;
    const char* Kh = (const char*)(Kb + hoff);
    const char* Vh = (const char*)(Vt + hoff);

    const float c2 = 0.06376390597f;   // 512^-0.5 * log2(e)

    // per-lane staging sources (inverse-swizzled), wave-uniform LDS dests
    const char* KsrcT = Kh + (tid >> 3) * 128 + (((tid & 7) ^ ((tid >> 3) & 7)) << 4);
    const char* VsrcT = Vh + (size_t)w * 2048 + ((lane ^ w) << 4);
    char* KdstT = smK + (w << 10);
    char* VdstT = smV + (w << 10);

    // stage phase 0 (K rows 0..511; V cols 0..511)
#pragma unroll
    for (int c = 0; c < 8; ++c) GLL(KsrcT + c * 8192, KdstT + c * 8192);
#pragma unroll
    for (int c = 0; c < 8; ++c) GLL(VsrcT + c * 16384, VdstT + c * 8192);

    // Q fragments (2 q-halves of 16 rows), pre-scaled by c2
    bf16x8 qf[2][2];
#pragma unroll
    for (int qh = 0; qh < 2; ++qh) {
        const bf16_t* qp = Qh + (q0 + qh * 16 + l15) * 64 + g * 8;
        bf16x8 a = *(const bf16x8*)(qp);
        bf16x8 bq = *(const bf16x8*)(qp + 32);
#pragma unroll
        for (int j = 0; j < 8; ++j) {
            a[j] = (bf16_t)((float)a[j] * c2);
            bq[j] = (bf16_t)((float)bq[j] * c2);
        }
        qf[qh][0] = a; qf[qh][1] = bq;
    }

    f32x4 oacc[2][4] = {};
    float denom[2] = { 0.f, 0.f };
    const f32x4 minit = { -4.0f, -4.0f, -4.0f, -4.0f };

    const int ke0 = (g ^ l7) << 4;   // K read 16B-unit (swizzle applied)

    __syncthreads();   // phase-0 data ready

#pragma unroll 1
    for (int phase = 0; phase < 2; ++phase) {
#pragma unroll 2
        for (int sub = 0; sub < 32; ++sub) {
            const char* krp = smK + (sub * 16 + l15) * 128;
            bf16x8 ka0 = *(const bf16x8*)(krp + ke0);
            bf16x8 ka1 = *(const bf16x8*)(krp + (ke0 ^ 64));
            bf16x4 pb[2];
#pragma unroll
            for (int qh = 0; qh < 2; ++qh) {
                f32x4 st = __builtin_amdgcn_mfma_f32_16x16x32_bf16(ka0, qf[qh][0], minit, 0, 0, 0);
                st = __builtin_amdgcn_mfma_f32_16x16x32_bf16(ka1, qf[qh][1], st, 0, 0, 0);
                float p0 = fexp2(st[0]), p1 = fexp2(st[1]), p2 = fexp2(st[2]), p3 = fexp2(st[3]);
                denom[qh] += (p0 + p1) + (p2 + p3);
                bf16x4 pv = { (bf16_t)p0, (bf16_t)p1, (bf16_t)p2, (bf16_t)p3 };
                pb[qh] = pv;
            }
            const int vcol = (((sub * 2 + (g >> 1)) ^ l7) << 4) + ((g & 1) << 3);
            __builtin_amdgcn_s_setprio(1);
#pragma unroll
            for (int dt = 0; dt < 4; ++dt) {
                bf16x4 va = *(const bf16x4*)(smV + (dt * 16 + l15) * 1024 + vcol);
                oacc[0][dt] = mfma16x16x16_bf16(va, pb[0], oacc[0][dt]);
                oacc[1][dt] = mfma16x16x16_bf16(va, pb[1], oacc[1][dt]);
            }
            __builtin_amdgcn_s_setprio(0);
        }
        if (phase == 0) {
            __syncthreads();   // all waves done reading phase 0
#pragma unroll
            for (int c = 0; c < 8; ++c) GLL(KsrcT + 65536 + c * 8192, KdstT + c * 8192);
#pragma unroll
            for (int c = 0; c < 8; ++c) GLL(VsrcT + 1024 + c * 16384, VdstT + c * 8192);
            __syncthreads();   // phase-1 data ready
        }
    }

    // epilogue: reduce denominator across g-groups, normalize, store
    const int b = head >> 3, h = head & 7;
#pragma unroll
    for (int qh = 0; qh < 2; ++qh) {
        float d0 = denom[qh];
        d0 += __shfl_xor(d0, 16);
        d0 += __shfl_xor(d0, 32);
        const float inv = 1.0f / d0;
        const int s = q0 + qh * 16 + l15;
        bf16_t* op = Ob + ((size_t)(b * 1024 + s)) * 512 + h * 64 + g * 4;
#pragma unroll
        for (int dt = 0; dt < 4; ++dt) {
            bf16x4 o = { (bf16_t)(oacc[qh][dt][0] * inv), (bf16_t)(oacc[qh][dt][1] * inv),
                         (bf16_t)(oacc[qh][dt][2] * inv), (bf16_t)(oacc[qh][dt][3] * inv) };
            *(bf16x4*)(op + dt * 16) = o;
        }
    }
}

// ---------------- kernel 3: LayerNorm over E=512, one wave per row ----------------
__global__ __launch_bounds__(256) void ln_kernel(const bf16_t* __restrict__ O,
                                                 const float* __restrict__ gamma,
                                                 const float* __restrict__ beta,
                                                 float* __restrict__ out) {
    const int w = threadIdx.x >> 6, lane = threadIdx.x & 63;
    const int row = blockIdx.x * 4 + w;
    const bf16_t* rp = O + (size_t)row * 512 + lane * 8;
    bf16x8 v8 = *(const bf16x8*)rp;
    float v[8];
    float sum = 0.0f, sq = 0.0f;
#pragma unroll
    for (int i = 0; i < 8; ++i) { v[i] = (float)v8[i]; sum += v[i]; sq += v[i] * v[i]; }
#pragma unroll
    for (int msk = 1; msk < 64; msk <<= 1) {
        sum += __shfl_xor(sum, msk);
        sq  += __shfl_xor(sq, msk);
    }
    const float mean = sum * (1.0f / 512.0f);
    const float var = sq * (1.0f / 512.0f) - mean * mean;
    const float rs = rsqrtf(var + 1e-5f);
    float4 g0 = *(const float4*)(gamma + lane * 8);
    float4 g1 = *(const float4*)(gamma + lane * 8 + 4);
    float4 b0 = *(const float4*)(beta + lane * 8);
    float4 b1 = *(const float4*)(beta + lane * 8 + 4);
    float* op = out + (size_t)row * 512 + lane * 8;
    float4 o0, o1;
    o0.x = (v[0] - mean) * rs * g0.x + b0.x;
    o0.y = (v[1] - mean) * rs * g0.y + b0.y;
    o0.z = (v[2] - mean) * rs * g0.z + b0.z;
    o0.w = (v[3] - mean) * rs * g0.w + b0.w;
    o1.x = (v[4] - mean) * rs * g1.x + b1.x;
    o1.y = (v[5] - mean) * rs * g1.y + b1.y;
    o1.z = (v[6] - mean) * rs * g1.z + b1.z;
    o1.w = (v[7] - mean) * rs * g1.w + b1.w;
    *(float4*)op = o0;
    *(float4*)(op + 4) = o1;
}

extern "C" void kernel_launch(void* const* d_in, const int* in_sizes, int n_in,
                              void* d_out, int out_size, void* d_ws, size_t ws_size,
                              hipStream_t stream) {
    const float* x  = (const float*)d_in[0];
    const float* wq = (const float*)d_in[1];
    const float* wk = (const float*)d_in[2];
    const float* wv = (const float*)d_in[3];
    const float* gamma = (const float*)d_in[4];
    const float* beta  = (const float*)d_in[5];
    float* out = (float*)d_out;

    char* ws = (char*)d_ws;
    bf16_t* xb   = (bf16_t*)(ws);                 //  8 MB  [8192,512]
    bf16_t* wall = (bf16_t*)(ws + 8388608);       //  1.5MB [1536,512]
    bf16_t* Qb   = (bf16_t*)(ws + 9961472);       //  8 MB  [B,H,S,D]
    bf16_t* Kb   = (bf16_t*)(ws + 18350080);      //  8 MB  [B,H,S,D]
    bf16_t* Vt   = (bf16_t*)(ws + 26738688);      //  8 MB  [B,H,D,S]
    bf16_t* Ob   = (bf16_t*)(ws + 35127296);      //  8 MB  [B,S,E]

    hipLaunchKernelGGL(cvt_kernel,  dim3(1024), dim3(256), 0, stream, x, wq, wk, wv, xb, wall);
    hipLaunchKernelGGL(proj_kernel, dim3(768),  dim3(256), 0, stream, xb, wall, Qb, Kb, Vt);
    hipLaunchKernelGGL(attn_kernel, dim3(256),  dim3(512), 0, stream, Qb, Kb, Vt, Ob);
    hipLaunchKernelGGL(ln_kernel,   dim3(2048), dim3(256), 0, stream, Ob, gamma, beta, out);
}

// Round 14
// 65.461 us; speedup vs baseline: 1.0568x; 1.0568x over previous
//
#include <hip/hip_runtime.h>
#include <hip/hip_bf16.h>

typedef __bf16 bf16_t;
typedef __bf16 bf16x4 __attribute__((ext_vector_type(4)));
typedef __bf16 bf16x8 __attribute__((ext_vector_type(8)));
typedef float  f32x4  __attribute__((ext_vector_type(4)));
typedef short  short4v __attribute__((ext_vector_type(4)));

#define GLL(gp, lp) __builtin_amdgcn_global_load_lds((const __attribute__((address_space(1))) void*)(gp), (__attribute__((address_space(3))) void*)(lp), 16, 0, 0)

__device__ __forceinline__ f32x4 mfma16x16x16_bf16(bf16x4 a, bf16x4 b, f32x4 c) {
#if __has_builtin(__builtin_amdgcn_mfma_f32_16x16x16_bf16)
    return __builtin_amdgcn_mfma_f32_16x16x16_bf16(a, b, c, 0, 0, 0);
#else
    return __builtin_amdgcn_mfma_f32_16x16x16bf16_1k(__builtin_bit_cast(short4v, a), __builtin_bit_cast(short4v, b), c, 0, 0, 0);
#endif
}

__device__ __forceinline__ float fexp2(float x) {
#if __has_builtin(__builtin_amdgcn_exp2f)
    return __builtin_amdgcn_exp2f(x);
#else
    return exp2f(x);
#endif
}

// ---------------- kernel 0: f32 -> bf16 convert ----------------
__global__ __launch_bounds__(256) void cvt_kernel(const float* __restrict__ x,
                                                  const float* __restrict__ wq,
                                                  const float* __restrict__ wk,
                                                  const float* __restrict__ wv,
                                                  bf16_t* __restrict__ xb,
                                                  bf16_t* __restrict__ wall) {
    const int TOT4 = 1245184;
    for (int i = blockIdx.x * blockDim.x + threadIdx.x; i < TOT4; i += gridDim.x * blockDim.x) {
        const float* src; bf16_t* dst; int off;
        if (i < 1048576) { src = x; dst = xb; off = i; }
        else {
            int j = i - 1048576;
            int wsel = j >> 16;
            off = j & 65535;
            src = (wsel == 0) ? wq : ((wsel == 1) ? wk : wv);
            dst = wall + ((size_t)wsel << 18);
        }
        float4 v = *(const float4*)(src + (size_t)off * 4);
        bf16x4 o = { (bf16_t)v.x, (bf16_t)v.y, (bf16_t)v.z, (bf16_t)v.w };
        *(bf16x4*)(dst + (size_t)off * 4) = o;
    }
}

// ---------------- kernel 1: fused QKV projection GEMM v3 (swizzled, verified R9/R10) ------
__global__ __launch_bounds__(256) void proj_kernel(const bf16_t* __restrict__ xb,
                                                   const bf16_t* __restrict__ wall,
                                                   bf16_t* __restrict__ Qb,
                                                   bf16_t* __restrict__ Kb,
                                                   bf16_t* __restrict__ Vt) {
    __shared__ char psm[34816];

    const int tid = threadIdx.x;
    const int w = tid >> 6, lane = tid & 63;
    const int bx = blockIdx.x;
    const int nb = bx % 12, mb = bx / 12;
    const int n0 = nb * 128, m0 = mb * 128;
    const int wn = w & 1, wm = w >> 1;
    const int l15 = lane & 15, g = lane >> 4;

    const int srow = w * 32 + (lane >> 2);
    const int kcol = (((lane & 3) ^ ((lane >> 3) & 3)) << 3);   // inverse-swizzled k-unit
    const bf16_t* wsrc0 = wall + (size_t)(n0 + srow) * 512 + kcol;
    const bf16_t* xsrc0 = xb + (size_t)(m0 + srow) * 512 + kcol;

    f32x4 acc[4][4] = {};

    {
        bf16_t* lw = (bf16_t*)(psm) + w * 1024;
        bf16_t* lx = (bf16_t*)(psm + 8192) + w * 1024;
        GLL(wsrc0, lw);
        GLL(wsrc0 + 8192, lw + 512);
        GLL(xsrc0, lx);
        GLL(xsrc0 + 8192, lx + 512);
    }
    __syncthreads();

    const int s4 = (l15 >> 1) & 3;   // read-side unit swizzle key

    for (int kt = 0; kt < 16; ++kt) {
        const int buf = kt & 1;
        if (kt < 15) {
            const int ko = (kt + 1) * 32;
            bf16_t* lw = (bf16_t*)(psm + (buf ^ 1) * 16384) + w * 1024;
            bf16_t* lx = (bf16_t*)(psm + (buf ^ 1) * 16384 + 8192) + w * 1024;
            GLL(wsrc0 + ko, lw);
            GLL(wsrc0 + 8192 + ko, lw + 512);
            GLL(xsrc0 + ko, lx);
            GLL(xsrc0 + 8192 + ko, lx + 512);
        }
        const bf16_t* sW = (const bf16_t*)(psm + buf * 16384);
        const bf16_t* sX = (const bf16_t*)(psm + buf * 16384 + 8192);

        bf16x8 af[4], bfv[4];
#pragma unroll
        for (int ni = 0; ni < 4; ++ni)
            af[ni] = *(const bf16x8*)(sW + (wn * 64 + ni * 16 + l15) * 32 + ((g ^ s4) << 3));
#pragma unroll
        for (int mi = 0; mi < 4; ++mi)
            bfv[mi] = *(const bf16x8*)(sX + (wm * 64 + mi * 16 + l15) * 32 + ((g ^ s4) << 3));
#pragma unroll
        for (int ni = 0; ni < 4; ++ni)
#pragma unroll
            for (int mi = 0; mi < 4; ++mi)
                acc[ni][mi] = __builtin_amdgcn_mfma_f32_16x16x32_bf16(af[ni], bfv[mi], acc[ni][mi], 0, 0, 0);
        __syncthreads();
    }

    const int which = n0 >> 9;   // 0=Q, 1=K, 2=V
    if (which < 2) {
        bf16_t* dst = (which == 0) ? Qb : Kb;
#pragma unroll
        for (int ni = 0; ni < 4; ++ni) {
#pragma unroll
            for (int mi = 0; mi < 4; ++mi) {
                int j = (n0 & 511) + wn * 64 + ni * 16 + g * 4;
                int h = j >> 6, dd = j & 63;
                int sb = m0 + wm * 64 + mi * 16 + l15;
                int b = sb >> 10, s = sb & 1023;
                bf16x4 o = { (bf16_t)acc[ni][mi][0], (bf16_t)acc[ni][mi][1],
                             (bf16_t)acc[ni][mi][2], (bf16_t)acc[ni][mi][3] };
                *(bf16x4*)(dst + ((size_t)((b * 8 + h) * 1024 + s)) * 64 + dd) = o;
            }
        }
    } else {
        bf16_t* ctile = (bf16_t*)psm;
#pragma unroll
        for (int ni = 0; ni < 4; ++ni)
#pragma unroll
            for (int mi = 0; mi < 4; ++mi)
#pragma unroll
                for (int r = 0; r < 4; ++r)
                    ctile[(wn * 64 + ni * 16 + g * 4 + r) * 136 + wm * 64 + mi * 16 + l15] =
                        (bf16_t)acc[ni][mi][r];
        __syncthreads();
        const int rr = tid >> 1, half = tid & 1;
        const int jv = (n0 & 511) + rr;
        const int hh = jv >> 6, dd = jv & 63;
        const int b = m0 >> 10, sb = (m0 & 1023) + half * 64;
        bf16_t* dst = Vt + ((size_t)((b * 8 + hh) * 64 + dd)) * 1024 + sb;
        const bf16_t* src = ctile + rr * 136 + half * 64;
#pragma unroll
        for (int u = 0; u < 8; ++u)
            *(bf16x8*)(dst + u * 8) = *(const bf16x8*)(src + u * 8);
    }
}

// ---------------- kernel 2: flash attention v5 (resident K/V, 3 barriers — best measured) --
// Block = (head, q-quarter): 8 waves x QBLK=32 = 256 q-rows. Grid 256 (1 block/CU),
// bx&7 == head&7 so a head's 4 blocks share an XCD. K/V streamed in 2 phases of 512 keys,
// each phase fully resident in LDS (K 64KB + V 64KB). Constant-m softmax (m=4 in MFMA
// C-init, exp2 domain); denominator via ones-MFMA (rides the under-utilized MFMA pipe —
// moving it to VALU regressed, R13).
__global__ __launch_bounds__(512, 2) void attn_kernel(const bf16_t* __restrict__ Qb,
                                                      const bf16_t* __restrict__ Kb,
                                                      const bf16_t* __restrict__ Vt,
                                                      bf16_t* __restrict__ Ob) {
    __shared__ char smK[65536];   // [512 keys][128B], 16B units XOR-swizzled by (row&7)
    __shared__ char smV[65536];   // [64 d][1024B],    16B units XOR-swizzled by (row&7)
    const int tid = threadIdx.x;
    const int w = tid >> 6, lane = tid & 63;
    const int l15 = lane & 15, g = lane >> 4, l7 = lane & 7;

    const int bx = blockIdx.x;        // 256
    const int head = bx & 63;         // bx&7 = head&7 -> XCD-local head group
    const int qq = bx >> 6;           // 0..3
    const int q0 = qq * 256 + w * 32;

    const size_t hoff = (size_t)head << 16;
    const bf16_t* Qh = Qb + hoff;
    const char* Kh = (const char*)(Kb + hoff);
    const char* Vh = (const char*)(Vt + hoff);

    const float c2 = 0.06376390597f;   // 512^-0.5 * log2(e)

    // per-lane staging sources (inverse-swizzled), wave-uniform LDS dests
    const char* KsrcT = Kh + (tid >> 3) * 128 + (((tid & 7) ^ ((tid >> 3) & 7)) << 4);
    const char* VsrcT = Vh + (size_t)w * 2048 + ((lane ^ w) << 4);
    char* KdstT = smK + (w << 10);
    char* VdstT = smV + (w << 10);

    // stage phase 0 (K rows 0..511; V cols 0..511)
#pragma unroll
    for (int c = 0; c < 8; ++c) GLL(KsrcT + c * 8192, KdstT + c * 8192);
#pragma unroll
    for (int c = 0; c < 8; ++c) GLL(VsrcT + c * 16384, VdstT + c * 8192);

    // Q fragments (2 q-halves of 16 rows), pre-scaled by c2
    bf16x8 qf[2][2];
#pragma unroll
    for (int qh = 0; qh < 2; ++qh) {
        const bf16_t* qp = Qh + (q0 + qh * 16 + l15) * 64 + g * 8;
        bf16x8 a = *(const bf16x8*)(qp);
        bf16x8 bq = *(const bf16x8*)(qp + 32);
#pragma unroll
        for (int j = 0; j < 8; ++j) {
            a[j] = (bf16_t)((float)a[j] * c2);
            bq[j] = (bf16_t)((float)bq[j] * c2);
        }
        qf[qh][0] = a; qf[qh][1] = bq;
    }

    f32x4 oacc[2][4] = {};
    f32x4 dacc[2] = {};
    const bf16x4 ones = { (bf16_t)1.0f, (bf16_t)1.0f, (bf16_t)1.0f, (bf16_t)1.0f };
    const f32x4 minit = { -4.0f, -4.0f, -4.0f, -4.0f };

    const int ke0 = (g ^ l7) << 4;   // K read 16B-unit (swizzle applied)

    __syncthreads();   // phase-0 data ready

#pragma unroll 1
    for (int phase = 0; phase < 2; ++phase) {
#pragma unroll 2
        for (int sub = 0; sub < 32; ++sub) {
            const char* krp = smK + (sub * 16 + l15) * 128;
            bf16x8 ka0 = *(const bf16x8*)(krp + ke0);
            bf16x8 ka1 = *(const bf16x8*)(krp + (ke0 ^ 64));
            bf16x4 pb[2];
#pragma unroll
            for (int qh = 0; qh < 2; ++qh) {
                f32x4 st = __builtin_amdgcn_mfma_f32_16x16x32_bf16(ka0, qf[qh][0], minit, 0, 0, 0);
                st = __builtin_amdgcn_mfma_f32_16x16x32_bf16(ka1, qf[qh][1], st, 0, 0, 0);
                bf16x4 pv = { (bf16_t)fexp2(st[0]), (bf16_t)fexp2(st[1]),
                              (bf16_t)fexp2(st[2]), (bf16_t)fexp2(st[3]) };
                pb[qh] = pv;
                dacc[qh] = mfma16x16x16_bf16(ones, pv, dacc[qh]);
            }
            const int vcol = (((sub * 2 + (g >> 1)) ^ l7) << 4) + ((g & 1) << 3);
#pragma unroll
            for (int dt = 0; dt < 4; ++dt) {
                bf16x4 va = *(const bf16x4*)(smV + (dt * 16 + l15) * 1024 + vcol);
                oacc[0][dt] = mfma16x16x16_bf16(va, pb[0], oacc[0][dt]);
                oacc[1][dt] = mfma16x16x16_bf16(va, pb[1], oacc[1][dt]);
            }
        }
        if (phase == 0) {
            __syncthreads();   // all waves done reading phase 0
#pragma unroll
            for (int c = 0; c < 8; ++c) GLL(KsrcT + 65536 + c * 8192, KdstT + c * 8192);
#pragma unroll
            for (int c = 0; c < 8; ++c) GLL(VsrcT + 1024 + c * 16384, VdstT + c * 8192);
            __syncthreads();   // phase-1 data ready
        }
    }

    // epilogue: normalize and store (O^T fragments -> [B,S,E] rows)
    const int b = head >> 3, h = head & 7;
#pragma unroll
    for (int qh = 0; qh < 2; ++qh) {
        const float inv = 1.0f / dacc[qh][0];
        const int s = q0 + qh * 16 + l15;
        bf16_t* op = Ob + ((size_t)(b * 1024 + s)) * 512 + h * 64 + g * 4;
#pragma unroll
        for (int dt = 0; dt < 4; ++dt) {
            bf16x4 o = { (bf16_t)(oacc[qh][dt][0] * inv), (bf16_t)(oacc[qh][dt][1] * inv),
                         (bf16_t)(oacc[qh][dt][2] * inv), (bf16_t)(oacc[qh][dt][3] * inv) };
            *(bf16x4*)(op + dt * 16) = o;
        }
    }
}

// ---------------- kernel 3: LayerNorm over E=512, one wave per row ----------------
__global__ __launch_bounds__(256) void ln_kernel(const bf16_t* __restrict__ O,
                                                 const float* __restrict__ gamma,
                                                 const float* __restrict__ beta,
                                                 float* __restrict__ out) {
    const int w = threadIdx.x >> 6, lane = threadIdx.x & 63;
    const int row = blockIdx.x * 4 + w;
    const bf16_t* rp = O + (size_t)row * 512 + lane * 8;
    bf16x8 v8 = *(const bf16x8*)rp;
    float v[8];
    float sum = 0.0f, sq = 0.0f;
#pragma unroll
    for (int i = 0; i < 8; ++i) { v[i] = (float)v8[i]; sum += v[i]; sq += v[i] * v[i]; }
#pragma unroll
    for (int msk = 1; msk < 64; msk <<= 1) {
        sum += __shfl_xor(sum, msk);
        sq  += __shfl_xor(sq, msk);
    }
    const float mean = sum * (1.0f / 512.0f);
    const float var = sq * (1.0f / 512.0f) - mean * mean;
    const float rs = rsqrtf(var + 1e-5f);
    float4 g0 = *(const float4*)(gamma + lane * 8);
    float4 g1 = *(const float4*)(gamma + lane * 8 + 4);
    float4 b0 = *(const float4*)(beta + lane * 8);
    float4 b1 = *(const float4*)(beta + lane * 8 + 4);
    float* op = out + (size_t)row * 512 + lane * 8;
    float4 o0, o1;
    o0.x = (v[0] - mean) * rs * g0.x + b0.x;
    o0.y = (v[1] - mean) * rs * g0.y + b0.y;
    o0.z = (v[2] - mean) * rs * g0.z + b0.z;
    o0.w = (v[3] - mean) * rs * g0.w + b0.w;
    o1.x = (v[4] - mean) * rs * g1.x + b1.x;
    o1.y = (v[5] - mean) * rs * g1.y + b1.y;
    o1.z = (v[6] - mean) * rs * g1.z + b1.z;
    o1.w = (v[7] - mean) * rs * g1.w + b1.w;
    *(float4*)op = o0;
    *(float4*)(op + 4) = o1;
}

extern "C" void kernel_launch(void* const* d_in, const int* in_sizes, int n_in,
                              void* d_out, int out_size, void* d_ws, size_t ws_size,
                              hipStream_t stream) {
    const float* x  = (const float*)d_in[0];
    const float* wq = (const float*)d_in[1];
    const float* wk = (const float*)d_in[2];
    const float* wv = (const float*)d_in[3];
    const float* gamma = (const float*)d_in[4];
    const float* beta  = (const float*)d_in[5];
    float* out = (float*)d_out;

    char* ws = (char*)d_ws;
    bf16_t* xb   = (bf16_t*)(ws);                 //  8 MB  [8192,512]
    bf16_t* wall = (bf16_t*)(ws + 8388608);       //  1.5MB [1536,512]
    bf16_t* Qb   = (bf16_t*)(ws + 9961472);       //  8 MB  [B,H,S,D]
    bf16_t* Kb   = (bf16_t*)(ws + 18350080);      //  8 MB  [B,H,S,D]
    bf16_t* Vt   = (bf16_t*)(ws + 26738688);      //  8 MB  [B,H,D,S]
    bf16_t* Ob   = (bf16_t*)(ws + 35127296);      //  8 MB  [B,S,E]

    hipLaunchKernelGGL(cvt_kernel,  dim3(1024), dim3(256), 0, stream, x, wq, wk, wv, xb, wall);
    hipLaunchKernelGGL(proj_kernel, dim3(768),  dim3(256), 0, stream, xb, wall, Qb, Kb, Vt);
    hipLaunchKernelGGL(attn_kernel, dim3(256),  dim3(512), 0, stream, Qb, Kb, Vt, Ob);
    hipLaunchKernelGGL(ln_kernel,   dim3(2048), dim3(256), 0, stream, Ob, gamma, beta, out);
}